// Round 1
// baseline (17278.989 us; speedup 1.0000x reference)
//
#include <hip/hip_runtime.h>
#include <cstdint>
#include <cstddef>

// Problem constants (match reference)
#define S_LEN 256
#define BB    32
#define EMBD  256
#define HID   256
#define NTAG  10
#define L_TOT (BB*S_LEN)      // 8192 flattened viterbi length
#define NEGV  -10000.0f
#define SOS_I 1
#define EOS_I 2

__device__ __forceinline__ float sigf(float x) { return 1.0f / (1.0f + expf(-x)); }

// ---------------------------------------------------------------------------
// prep: gather embeddings E[t*32+b][m] = emb[x[b][t]][m]
// ---------------------------------------------------------------------------
__global__ void prep_ebuf(const int* __restrict__ x, const float* __restrict__ emb,
                          float* __restrict__ E) {
    const int row = blockIdx.x;          // t*32 + b
    const int t = row >> 5, b = row & 31;
    const int xi = x[b * S_LEN + t];
    E[(size_t)row * EMBD + threadIdx.x] = emb[(size_t)xi * EMBD + threadIdx.x];
}

// prep: W_t[d][k][j], k<256 -> Wih_d[j][k], k>=256 -> Whh_d[j][k-256]  (k-major for lane loads)
__global__ void prep_wt(const float* __restrict__ Wih_f, const float* __restrict__ Whh_f,
                        const float* __restrict__ Wih_b, const float* __restrict__ Whh_b,
                        float* __restrict__ Wt) {
    const int dk = blockIdx.x;           // d*512 + k
    const int d = dk >> 9, k = dk & 511;
    const int j = threadIdx.x;           // 0..1023
    const float* src = (d == 0) ? ((k < 256) ? Wih_f : Whh_f)
                                : ((k < 256) ? Wih_b : Whh_b);
    const int kk = k & 255;
    Wt[(size_t)dk * 1024 + j] = src[(size_t)j * 256 + kk];
}

__global__ void prep_bias(const float* __restrict__ bih_f, const float* __restrict__ bhh_f,
                          const float* __restrict__ bih_b, const float* __restrict__ bhh_b,
                          float* __restrict__ bc) {
    const int idx = blockIdx.x * blockDim.x + threadIdx.x; // 0..2047
    if (idx < 1024) bc[idx] = bih_f[idx] + bhh_f[idx];
    else            bc[idx] = bih_b[idx - 1024] + bhh_b[idx - 1024];
}

// ---------------------------------------------------------------------------
// Persistent BiLSTM recurrence. 128 blocks = 2 dirs x 16 m-groups x 4 b-groups.
// 512 thr = 8 waves = (kq in 0..3: K-quarter of fused K=512) x (bh in 0..1: 4 batches).
// Lanes = (gate g in 0..3) x (m-local in 0..15) -> one gate row j per lane.
// W slice held in 128 VGPRs/lane; activations read as wave-uniform (scalar) loads.
// Grid barrier: monotonic counter in ws (device-scope atomics), all 128 blocks co-resident.
// ---------------------------------------------------------------------------
__global__ __launch_bounds__(512, 2) void lstm_rec(
    const float* __restrict__ E,      // [8192][256]
    const float* __restrict__ Wt,     // [2][512][1024]
    const float* __restrict__ bc,     // [2][1024]
    const float* __restrict__ hprev,  // alias of hout (read side, step s-1 only)
    float*       __restrict__ hout,   // [2][256][32][256]
    unsigned int* ctr) {
    const int blk = blockIdx.x;              // 0..127
    const int d  = blk >> 6;
    const int mg = (blk >> 2) & 15;
    const int bg = blk & 3;
    const int tid  = threadIdx.x;
    const int wave = __builtin_amdgcn_readfirstlane(tid >> 6); // 0..7, force SGPR
    const int lane = tid & 63;
    const int kq = wave & 3;
    const int bh = wave >> 2;
    const int g  = lane >> 4;
    const int ml = lane & 15;
    const int j  = g * 256 + mg * 16 + ml;   // gate-row index within dir
    const int k0 = kq * 128;                 // fused-K base (0,128 = e-part; 256,384 = h-part)

    // persistent weight slice: w[i] = W[d][j][k0+i]
    float w[128];
    {
        const float* wsrc = Wt + ((size_t)d * 512 + k0) * 1024 + j;
        #pragma unroll
        for (int i = 0; i < 128; ++i) w[i] = wsrc[(size_t)i * 1024];
    }

    __shared__ float part[8][4][64];   // [b_local][kq][lane]
    __shared__ float c_lds[8][16];     // persistent cell state for this block's slice
    __shared__ float bias_lds[64];
    if (tid < 64) bias_lds[tid] = bc[d * 1024 + (tid >> 4) * 256 + mg * 16 + (tid & 15)];

    const unsigned nblk = gridDim.x;

    #pragma unroll 1
    for (int s = 0; s < S_LEN; ++s) {
        const int t = d ? (S_LEN - 1 - s) : s;
        float acc[4] = {0.f, 0.f, 0.f, 0.f};
        if (kq < 2) {
            #pragma unroll
            for (int bi = 0; bi < 4; ++bi) {
                const int b = bg * 8 + bh * 4 + bi;
                const float* src = E + ((size_t)(t * 32 + b)) * 256 + k0;
                float a = 0.f;
                #pragma unroll
                for (int kk = 0; kk < 128; ++kk) a = fmaf(src[kk], w[kk], a);
                acc[bi] = a;
            }
        } else if (s > 0) {
            #pragma unroll
            for (int bi = 0; bi < 4; ++bi) {
                const int b = bg * 8 + bh * 4 + bi;
                const float* src = hprev + (((size_t)d * S_LEN + (s - 1)) * 32 + b) * 256 + (k0 - 256);
                float a = 0.f;
                #pragma unroll
                for (int kk = 0; kk < 128; ++kk) a = fmaf(src[kk], w[kk], a);
                acc[bi] = a;
            }
        }
        #pragma unroll
        for (int bi = 0; bi < 4; ++bi) part[bh * 4 + bi][kq][lane] = acc[bi];
        __syncthreads();

        if (tid < 128) {
            const int bl = tid >> 4, m = tid & 15;
            float vg[4];
            #pragma unroll
            for (int gg = 0; gg < 4; ++gg)
                vg[gg] = part[bl][0][gg * 16 + m] + part[bl][1][gg * 16 + m]
                       + part[bl][2][gg * 16 + m] + part[bl][3][gg * 16 + m]
                       + bias_lds[gg * 16 + m];
            const float iv = sigf(vg[0]);
            const float fv = sigf(vg[1]);
            const float gv = tanhf(vg[2]);
            const float ov = sigf(vg[3]);
            float c = (s == 0) ? 0.f : c_lds[bl][m];
            c = fv * c + iv * gv;
            c_lds[bl][m] = c;
            const float hv = ov * tanhf(c);
            hout[(((size_t)d * S_LEN + s) * 32 + (bg * 8 + bl)) * 256 + mg * 16 + m] = hv;
        }
        __syncthreads();

        if (s < S_LEN - 1) {
            if (tid == 0) {
                __threadfence();  // agent release: writeback L2 (cross-XCD)
                __hip_atomic_fetch_add(ctr, 1u, __ATOMIC_RELAXED, __HIP_MEMORY_SCOPE_AGENT);
                const unsigned tgt = nblk * (unsigned)(s + 1);
                while (__hip_atomic_load(ctr, __ATOMIC_RELAXED, __HIP_MEMORY_SCOPE_AGENT) < tgt) {
                    __builtin_amdgcn_s_sleep(2);
                }
                __threadfence();  // agent acquire: invalidate L2 before reading peers' h
            }
            __syncthreads();
        }
    }
}

// ---------------------------------------------------------------------------
// out[r][tag] = [hf | hb] . Wout[tag] + bout[tag],  r = b*256 + t
// ---------------------------------------------------------------------------
__global__ __launch_bounds__(128) void out_proj(const float* __restrict__ hh,
                                                const float* __restrict__ Wout,
                                                const float* __restrict__ bout,
                                                float* __restrict__ out) {
    const int r = blockIdx.x * blockDim.x + threadIdx.x; // 0..8191
    const int b = r >> 8, t = r & 255;
    const float* hf = hh + (((size_t)0 * S_LEN + t) * 32 + b) * 256;
    const float* hb = hh + (((size_t)1 * S_LEN + (S_LEN - 1 - t)) * 32 + b) * 256;
    float acc[NTAG];
    #pragma unroll
    for (int q = 0; q < NTAG; ++q) acc[q] = bout[q];
    for (int m = 0; m < HID; ++m) {
        const float hv = hf[m];
        #pragma unroll
        for (int q = 0; q < NTAG; ++q) acc[q] = fmaf(hv, Wout[q * 512 + m], acc[q]);
    }
    for (int m = 0; m < HID; ++m) {
        const float hv = hb[m];
        #pragma unroll
        for (int q = 0; q < NTAG; ++q) acc[q] = fmaf(hv, Wout[q * 512 + 256 + m], acc[q]);
    }
    #pragma unroll
    for (int q = 0; q < NTAG; ++q) out[(size_t)r * NTAG + q] = acc[q];
}

// ---------------------------------------------------------------------------
// Viterbi forward values (sequential, exact reference arithmetic per step:
// one add per (to,from), exact max, one add of feat). Lanes 0..9 = 'to'.
// Stores fv history for the parallel backpointer kernel.
// ---------------------------------------------------------------------------
__global__ __launch_bounds__(64) void viterbi_fv(const float* __restrict__ feats,
                                                 const float* __restrict__ trans,
                                                 float* __restrict__ fvh,
                                                 float* __restrict__ score_out,
                                                 int* __restrict__ best_out) {
    const int lane = threadIdx.x;
    float trow[NTAG];
    #pragma unroll
    for (int f = 0; f < NTAG; ++f) trow[f] = (lane < NTAG) ? trans[lane * NTAG + f] : 0.f;
    float fv[NTAG];
    #pragma unroll
    for (int f = 0; f < NTAG; ++f) fv[f] = (f == SOS_I) ? 0.f : NEGV;
    float feat = (lane < NTAG) ? feats[lane] : 0.f;

    for (int r = 0; r < L_TOT; ++r) {
        const float fnext = (r + 1 < L_TOT && lane < NTAG) ? feats[(size_t)(r + 1) * NTAG + lane] : 0.f;
        float sc[NTAG];
        #pragma unroll
        for (int f = 0; f < NTAG; ++f) sc[f] = fv[f] + trow[f];
        float m = fmaxf(fmaxf(fmaxf(fmaxf(sc[0], sc[1]), fmaxf(sc[2], sc[3])),
                              fmaxf(fmaxf(sc[4], sc[5]), fmaxf(sc[6], sc[7]))),
                        fmaxf(sc[8], sc[9]));
        const float fvnew = m + feat;
        if (lane < NTAG) fvh[(size_t)r * NTAG + lane] = fvnew;
        #pragma unroll
        for (int f = 0; f < NTAG; ++f) fv[f] = __shfl(fvnew, f, 64);
        feat = fnext;
    }

    if (lane == 0) {
        float bm = fv[0] + trans[EOS_I * NTAG + 0];
        int ba = 0;
        #pragma unroll
        for (int f = 1; f < NTAG; ++f) {
            const float tv = fv[f] + trans[EOS_I * NTAG + f];
            if (tv > bm) { bm = tv; ba = f; }   // strict > => first-max tie rule
        }
        score_out[0] = bm;
        best_out[0] = ba;
    }
}

// Backpointers, fully parallel: bptr[r][to] = first-argmax_f (fv[r-1][f] + T[to][f])
__global__ void viterbi_bp(const float* __restrict__ fvh, const float* __restrict__ trans,
                           unsigned char* __restrict__ bp) {
    const int idx = blockIdx.x * blockDim.x + threadIdx.x;
    if (idx >= L_TOT * NTAG) return;
    const int r = idx / NTAG, to = idx - r * NTAG;
    float best = 0.f;
    int arg = 0;
    #pragma unroll
    for (int f = 0; f < NTAG; ++f) {
        const float fp = r ? fvh[(size_t)(r - 1) * NTAG + f] : ((f == SOS_I) ? 0.f : NEGV);
        const float s = fp + trans[to * NTAG + f];
        if (f == 0) best = s;
        else if (s > best) { best = s; arg = f; }  // strict > => first-max
    }
    bp[idx] = (unsigned char)arg;
}

// Chunked backtrace (exact function-composition scan over [10]->[10] maps)
__global__ __launch_bounds__(1024) void backtrace(const unsigned char* __restrict__ bp,
                                                  const int* __restrict__ best_in,
                                                  float* __restrict__ path_out) {
    __shared__ unsigned char fc[128 * NTAG];
    __shared__ unsigned char topt[128];
    const int tid = threadIdx.x;
    // phase 1: each chunk c (64 steps) composes its map for all 10 entries
    for (int pe = tid; pe < 128 * NTAG; pe += 1024) {
        const int c = pe / NTAG, e = pe - c * NTAG;
        int cur = e;
        for (int i = 63; i >= 0; --i) cur = bp[(size_t)(c * 64 + i) * NTAG + cur];
        fc[c * NTAG + e] = (unsigned char)cur;
    }
    __syncthreads();
    // phase 2: serial over 128 chunks
    if (tid == 0) {
        int carry = best_in[0];
        for (int c = 127; c >= 0; --c) {
            topt[c] = (unsigned char)carry;
            carry = fc[c * NTAG + carry];
        }
    }
    __syncthreads();
    // phase 3: emit interior paths per chunk
    for (int c = tid; c < 128; c += 1024) {
        int cur = topt[c];
        for (int i = 63; i >= 0; --i) {
            const int t = c * 64 + i;
            path_out[t] = (float)cur;
            cur = bp[(size_t)t * NTAG + cur];
        }
    }
}

// ---------------------------------------------------------------------------
extern "C" void kernel_launch(void* const* d_in, const int* in_sizes, int n_in,
                              void* d_out, int out_size, void* d_ws, size_t ws_size,
                              hipStream_t stream) {
    const int*   x     = (const int*)d_in[0];
    // d_in[1] = x_lengths (unused: all full), d_in[2] = y (unused)
    const float* emb   = (const float*)d_in[3];
    const float* Wih_f = (const float*)d_in[4];
    const float* Whh_f = (const float*)d_in[5];
    const float* bih_f = (const float*)d_in[6];
    const float* bhh_f = (const float*)d_in[7];
    const float* Wih_b = (const float*)d_in[8];
    const float* Whh_b = (const float*)d_in[9];
    const float* bih_b = (const float*)d_in[10];
    const float* bhh_b = (const float*)d_in[11];
    const float* Wout  = (const float*)d_in[12];
    const float* bout  = (const float*)d_in[13];
    const float* trans = (const float*)d_in[14];

    char* ws = (char*)d_ws;
    size_t off = 0;
    auto alloc = [&](size_t bytes) { void* p = ws + off; off += (bytes + 255) & ~(size_t)255; return p; };
    unsigned*      ctr  = (unsigned*)alloc(256);
    int*           best = (int*)alloc(256);
    float*         E    = (float*)alloc((size_t)L_TOT * EMBD * 4);       // 8.4 MB
    float*         Wt   = (float*)alloc((size_t)2 * 512 * 1024 * 4);     // 4 MB
    float*         bc   = (float*)alloc(2048 * 4);
    float*         hh   = (float*)alloc((size_t)2 * S_LEN * BB * HID * 4); // 16.8 MB
    float*         fvh  = (float*)alloc((size_t)L_TOT * NTAG * 4);       // 328 KB
    unsigned char* bp   = (unsigned char*)alloc((size_t)L_TOT * NTAG);   // 80 KB

    float* out   = (float*)d_out;                  // [0 .. 81920)
    float* score = out + (size_t)L_TOT * NTAG;     // [81920]
    float* path  = score + 1;                      // [81921 .. 90113)

    hipMemsetAsync(ctr, 0, 4, stream);  // barrier counter must start at 0 every call
    hipLaunchKernelGGL(prep_ebuf, dim3(L_TOT), dim3(EMBD), 0, stream, x, emb, E);
    hipLaunchKernelGGL(prep_wt,   dim3(1024),  dim3(1024), 0, stream, Wih_f, Whh_f, Wih_b, Whh_b, Wt);
    hipLaunchKernelGGL(prep_bias, dim3(2),     dim3(1024), 0, stream, bih_f, bhh_f, bih_b, bhh_b, bc);
    hipLaunchKernelGGL(lstm_rec,  dim3(128),   dim3(512),  0, stream, E, Wt, bc, hh, hh, ctr);
    hipLaunchKernelGGL(out_proj,  dim3(L_TOT / 128), dim3(128), 0, stream, hh, Wout, bout, out);
    hipLaunchKernelGGL(viterbi_fv, dim3(1),    dim3(64),   0, stream, out, trans, fvh, score, best);
    hipLaunchKernelGGL(viterbi_bp, dim3((L_TOT * NTAG + 255) / 256), dim3(256), 0, stream, fvh, trans, bp);
    hipLaunchKernelGGL(backtrace, dim3(1),     dim3(1024), 0, stream, bp, best, path);
}

// Round 2
// 12489.257 us; speedup vs baseline: 1.3835x; 1.3835x over previous
//
#include <hip/hip_runtime.h>
#include <cstdint>
#include <cstddef>

// Problem constants (match reference)
#define S_LEN 256
#define BB    32
#define EMBD  256
#define HID   256
#define NTAG  10
#define L_TOT (BB*S_LEN)      // 8192 flattened viterbi length
#define NEGV  -10000.0f
#define SOS_I 1
#define EOS_I 2

__device__ __forceinline__ float sigf(float x) { return 1.0f / (1.0f + expf(-x)); }

// ---------------------------------------------------------------------------
// prep: gather embeddings E[t*32+b][m] = emb[x[b][t]][m]
// ---------------------------------------------------------------------------
__global__ void prep_ebuf(const int* __restrict__ x, const float* __restrict__ emb,
                          float* __restrict__ E) {
    const int row = blockIdx.x;          // t*32 + b
    const int t = row >> 5, b = row & 31;
    const int xi = x[b * S_LEN + t];
    E[(size_t)row * EMBD + threadIdx.x] = emb[(size_t)xi * EMBD + threadIdx.x];
}

// prep: Wt[d][k][j], k<256 -> Wih_d[j][k], k>=256 -> Whh_d[j][k-256]  (k-major)
__global__ void prep_wt(const float* __restrict__ Wih_f, const float* __restrict__ Whh_f,
                        const float* __restrict__ Wih_b, const float* __restrict__ Whh_b,
                        float* __restrict__ Wt) {
    const int dk = blockIdx.x;           // d*512 + k
    const int d = dk >> 9, k = dk & 511;
    const int j = threadIdx.x;           // 0..1023
    const float* src = (d == 0) ? ((k < 256) ? Wih_f : Whh_f)
                                : ((k < 256) ? Wih_b : Whh_b);
    const int kk = k & 255;
    Wt[(size_t)dk * 1024 + j] = src[(size_t)j * 256 + kk];
}

__global__ void prep_bias(const float* __restrict__ bih_f, const float* __restrict__ bhh_f,
                          const float* __restrict__ bih_b, const float* __restrict__ bhh_b,
                          float* __restrict__ bc) {
    const int idx = blockIdx.x * blockDim.x + threadIdx.x; // 0..2047
    if (idx < 1024) bc[idx] = bih_f[idx] + bhh_f[idx];
    else            bc[idx] = bih_b[idx - 1024] + bhh_b[idx - 1024];
}

// ---------------------------------------------------------------------------
// Persistent BiLSTM recurrence. 128 blocks; group g = blk&7 encodes
// (d = g>>2, bg = g&3); member mg = blk>>3 in 0..15 (m-slice of 16).
// Sync domain = the 16 blocks sharing g (same XCD under round-robin dispatch;
// device-scope atomics keep it correct regardless of actual mapping).
// 512 thr = 8 waves = kq(4: fused-K quarter of 128) x bh(2: 4 batches).
// Lane = gate-row j (64 rows: 4 gates x 16 m). w[128] persistent in VGPRs.
// Operands staged per step into transposed LDS st[k][b] (pad 12);
// inner loop: 1 uniform ds_read_b128 (4 batches) + 4 fma per k.
// ---------------------------------------------------------------------------
__global__ __launch_bounds__(512, 1) void lstm_rec(
    const float* __restrict__ E,      // [8192 rows t*32+b][256]
    const float* __restrict__ Wt,     // [2][512][1024]
    const float* __restrict__ bc,     // [2][1024]
    float* __restrict__ hh,           // [2][256 s][32 b][256 m]
    unsigned int* ctr) {              // 8 counters, 256B apart
    const int blk = blockIdx.x;
    const int g   = blk & 7;
    const int mg  = blk >> 3;
    const int d   = g >> 2;
    const int bg  = g & 3;
    const int tid = threadIdx.x;
    const int wave = __builtin_amdgcn_readfirstlane(tid >> 6);
    const int lane = tid & 63;
    const int kq = wave & 3;                  // fused-K quarter (0,1=e; 2,3=h)
    const int bh = wave >> 2;                 // batch half (4 batches)
    const int jg = (lane >> 4) * 256 + mg * 16 + (lane & 15);

    // persistent weights: w[i] = Wt[d][kq*128 + i][jg]
    float w[128];
    {
        const float* wsrc = Wt + ((size_t)d * 512 + kq * 128) * 1024 + jg;
        #pragma unroll
        for (int i = 0; i < 128; ++i) w[i] = wsrc[(size_t)i * 1024];
    }

    __shared__ __align__(16) float st[512][12];   // [k-fused][b_local], pad 12
    __shared__ float part[8][4][66];              // [b_local][kq][lane], pad 66
    __shared__ float cst[8][16];
    __shared__ float bias[64];
    if (tid < 64) bias[tid] = bc[d * 1024 + (tid >> 4) * 256 + mg * 16 + (tid & 15)];

    // stage e for s=0 (wave = batch slot)
    {
        const int t0 = d ? (S_LEN - 1) : 0;
        const float* src = E + ((size_t)(t0 * 32) + bg * 8 + wave) * 256;
        #pragma unroll
        for (int q = 0; q < 4; ++q) st[q * 64 + lane][wave] = src[q * 64 + lane];
    }
    __syncthreads();

    unsigned int* myctr = ctr + g * 64;

    #pragma unroll 1
    for (int s = 0; s < S_LEN; ++s) {
        float acc[4] = {0.f, 0.f, 0.f, 0.f};
        if (!(kq >= 2 && s == 0)) {           // h-part is zero at s=0
            const float* base = &st[kq * 128][bh * 4];
            #pragma unroll
            for (int i = 0; i < 128; ++i) {
                const float4 hv = *(const float4*)(base + i * 12);
                acc[0] = fmaf(hv.x, w[i], acc[0]);
                acc[1] = fmaf(hv.y, w[i], acc[1]);
                acc[2] = fmaf(hv.z, w[i], acc[2]);
                acc[3] = fmaf(hv.w, w[i], acc[3]);
            }
        }
        #pragma unroll
        for (int bi = 0; bi < 4; ++bi) part[bh * 4 + bi][kq][lane] = acc[bi];
        __syncthreads();

        if (tid < 128) {
            const int bl = tid >> 4, m = tid & 15;
            float vg[4];
            #pragma unroll
            for (int gg = 0; gg < 4; ++gg)
                vg[gg] = part[bl][0][gg * 16 + m] + part[bl][1][gg * 16 + m]
                       + part[bl][2][gg * 16 + m] + part[bl][3][gg * 16 + m]
                       + bias[gg * 16 + m];
            const float iv = sigf(vg[0]);
            const float fv = sigf(vg[1]);
            const float gv = tanhf(vg[2]);
            const float ov = sigf(vg[3]);
            float c = (s == 0) ? 0.f : cst[bl][m];
            c = fv * c + iv * gv;
            cst[bl][m] = c;
            hh[(((size_t)d * S_LEN + s) * 32 + (bg * 8 + bl)) * 256 + mg * 16 + m] = ov * tanhf(c);
        }
        __syncthreads();   // post done; h stores drained (vmcnt(0) before barrier)

        if (s < S_LEN - 1) {
            // stage e for step s+1 (independent of h) -> overlaps the barrier wait
            {
                const int t1 = d ? (S_LEN - 2 - s) : (s + 1);
                const float* src = E + ((size_t)(t1 * 32) + bg * 8 + wave) * 256;
                #pragma unroll
                for (int q = 0; q < 4; ++q) st[q * 64 + lane][wave] = src[q * 64 + lane];
            }
            if (tid == 0) {
                __threadfence();   // release: L2 writeback (cross-XCD visibility)
                __hip_atomic_fetch_add(myctr, 1u, __ATOMIC_RELAXED, __HIP_MEMORY_SCOPE_AGENT);
                const unsigned tgt = 16u * (unsigned)(s + 1);
                while (__hip_atomic_load(myctr, __ATOMIC_RELAXED, __HIP_MEMORY_SCOPE_AGENT) < tgt)
                    __builtin_amdgcn_s_sleep(2);
                __threadfence();   // acquire: invalidate caches before reading peers' h
            }
            __syncthreads();
            // stage h of step s (now visible)
            {
                const float* src = hh + (((size_t)d * S_LEN + s) * 32 + bg * 8 + wave) * 256;
                #pragma unroll
                for (int q = 0; q < 4; ++q) st[256 + q * 64 + lane][wave] = src[q * 64 + lane];
            }
            __syncthreads();
        }
    }
}

// ---------------------------------------------------------------------------
// out[r][tag] = [hf | hb] . Wout[tag] + bout[tag],  r = b*256 + t
// ---------------------------------------------------------------------------
__global__ __launch_bounds__(128) void out_proj(const float* __restrict__ hh,
                                                const float* __restrict__ Wout,
                                                const float* __restrict__ bout,
                                                float* __restrict__ out) {
    const int r = blockIdx.x * blockDim.x + threadIdx.x; // 0..8191
    const int b = r >> 8, t = r & 255;
    const float* hf = hh + (((size_t)0 * S_LEN + t) * 32 + b) * 256;
    const float* hb = hh + (((size_t)1 * S_LEN + (S_LEN - 1 - t)) * 32 + b) * 256;
    float acc[NTAG];
    #pragma unroll
    for (int q = 0; q < NTAG; ++q) acc[q] = bout[q];
    for (int m = 0; m < HID; ++m) {
        const float hv = hf[m];
        #pragma unroll
        for (int q = 0; q < NTAG; ++q) acc[q] = fmaf(hv, Wout[q * 512 + m], acc[q]);
    }
    for (int m = 0; m < HID; ++m) {
        const float hv = hb[m];
        #pragma unroll
        for (int q = 0; q < NTAG; ++q) acc[q] = fmaf(hv, Wout[q * 512 + 256 + m], acc[q]);
    }
    #pragma unroll
    for (int q = 0; q < NTAG; ++q) out[(size_t)r * NTAG + q] = acc[q];
}

// ---------------------------------------------------------------------------
// Viterbi forward values (sequential, exact reference arithmetic per step).
// Lanes 0..9 = 'to'. Stores fv history for the parallel backpointer kernel.
// ---------------------------------------------------------------------------
__global__ __launch_bounds__(64) void viterbi_fv(const float* __restrict__ feats,
                                                 const float* __restrict__ trans,
                                                 float* __restrict__ fvh,
                                                 float* __restrict__ score_out,
                                                 int* __restrict__ best_out) {
    const int lane = threadIdx.x;
    float trow[NTAG];
    #pragma unroll
    for (int f = 0; f < NTAG; ++f) trow[f] = (lane < NTAG) ? trans[lane * NTAG + f] : 0.f;
    float fv[NTAG];
    #pragma unroll
    for (int f = 0; f < NTAG; ++f) fv[f] = (f == SOS_I) ? 0.f : NEGV;
    float feat = (lane < NTAG) ? feats[lane] : 0.f;

    for (int r = 0; r < L_TOT; ++r) {
        const float fnext = (r + 1 < L_TOT && lane < NTAG) ? feats[(size_t)(r + 1) * NTAG + lane] : 0.f;
        float sc[NTAG];
        #pragma unroll
        for (int f = 0; f < NTAG; ++f) sc[f] = fv[f] + trow[f];
        float m = fmaxf(fmaxf(fmaxf(fmaxf(sc[0], sc[1]), fmaxf(sc[2], sc[3])),
                              fmaxf(fmaxf(sc[4], sc[5]), fmaxf(sc[6], sc[7]))),
                        fmaxf(sc[8], sc[9]));
        const float fvnew = m + feat;
        if (lane < NTAG) fvh[(size_t)r * NTAG + lane] = fvnew;
        #pragma unroll
        for (int f = 0; f < NTAG; ++f) fv[f] = __shfl(fvnew, f, 64);
        feat = fnext;
    }

    if (lane == 0) {
        float bm = fv[0] + trans[EOS_I * NTAG + 0];
        int ba = 0;
        #pragma unroll
        for (int f = 1; f < NTAG; ++f) {
            const float tv = fv[f] + trans[EOS_I * NTAG + f];
            if (tv > bm) { bm = tv; ba = f; }   // strict > => first-max tie rule
        }
        score_out[0] = bm;
        best_out[0] = ba;
    }
}

// Backpointers, fully parallel: bptr[r][to] = first-argmax_f (fv[r-1][f] + T[to][f])
__global__ void viterbi_bp(const float* __restrict__ fvh, const float* __restrict__ trans,
                           unsigned char* __restrict__ bp) {
    const int idx = blockIdx.x * blockDim.x + threadIdx.x;
    if (idx >= L_TOT * NTAG) return;
    const int r = idx / NTAG, to = idx - r * NTAG;
    float best = 0.f;
    int arg = 0;
    #pragma unroll
    for (int f = 0; f < NTAG; ++f) {
        const float fp = r ? fvh[(size_t)(r - 1) * NTAG + f] : ((f == SOS_I) ? 0.f : NEGV);
        const float s = fp + trans[to * NTAG + f];
        if (f == 0) best = s;
        else if (s > best) { best = s; arg = f; }  // strict > => first-max
    }
    bp[idx] = (unsigned char)arg;
}

// Chunked backtrace (exact function-composition scan over [10]->[10] maps)
__global__ __launch_bounds__(1024) void backtrace(const unsigned char* __restrict__ bp,
                                                  const int* __restrict__ best_in,
                                                  float* __restrict__ path_out) {
    __shared__ unsigned char fc[128 * NTAG];
    __shared__ unsigned char topt[128];
    const int tid = threadIdx.x;
    for (int pe = tid; pe < 128 * NTAG; pe += 1024) {
        const int c = pe / NTAG, e = pe - c * NTAG;
        int cur = e;
        for (int i = 63; i >= 0; --i) cur = bp[(size_t)(c * 64 + i) * NTAG + cur];
        fc[c * NTAG + e] = (unsigned char)cur;
    }
    __syncthreads();
    if (tid == 0) {
        int carry = best_in[0];
        for (int c = 127; c >= 0; --c) {
            topt[c] = (unsigned char)carry;
            carry = fc[c * NTAG + carry];
        }
    }
    __syncthreads();
    for (int c = tid; c < 128; c += 1024) {
        int cur = topt[c];
        for (int i = 63; i >= 0; --i) {
            const int t = c * 64 + i;
            path_out[t] = (float)cur;
            cur = bp[(size_t)t * NTAG + cur];
        }
    }
}

// ---------------------------------------------------------------------------
extern "C" void kernel_launch(void* const* d_in, const int* in_sizes, int n_in,
                              void* d_out, int out_size, void* d_ws, size_t ws_size,
                              hipStream_t stream) {
    const int*   x     = (const int*)d_in[0];
    const float* emb   = (const float*)d_in[3];
    const float* Wih_f = (const float*)d_in[4];
    const float* Whh_f = (const float*)d_in[5];
    const float* bih_f = (const float*)d_in[6];
    const float* bhh_f = (const float*)d_in[7];
    const float* Wih_b = (const float*)d_in[8];
    const float* Whh_b = (const float*)d_in[9];
    const float* bih_b = (const float*)d_in[10];
    const float* bhh_b = (const float*)d_in[11];
    const float* Wout  = (const float*)d_in[12];
    const float* bout  = (const float*)d_in[13];
    const float* trans = (const float*)d_in[14];

    char* ws = (char*)d_ws;
    size_t off = 0;
    auto alloc = [&](size_t bytes) { void* p = ws + off; off += (bytes + 255) & ~(size_t)255; return p; };
    unsigned*      ctr  = (unsigned*)alloc(8 * 256);                     // 8 group counters
    int*           best = (int*)alloc(256);
    float*         E    = (float*)alloc((size_t)L_TOT * EMBD * 4);       // 8.4 MB
    float*         Wt   = (float*)alloc((size_t)2 * 512 * 1024 * 4);     // 4 MB
    float*         bc   = (float*)alloc(2048 * 4);
    float*         hh   = (float*)alloc((size_t)2 * S_LEN * BB * HID * 4); // 16.8 MB
    float*         fvh  = (float*)alloc((size_t)L_TOT * NTAG * 4);       // 328 KB
    unsigned char* bp   = (unsigned char*)alloc((size_t)L_TOT * NTAG);   // 80 KB

    float* out   = (float*)d_out;                  // [0 .. 81920)
    float* score = out + (size_t)L_TOT * NTAG;     // [81920]
    float* path  = score + 1;                      // [81921 .. 90113)

    hipMemsetAsync(ctr, 0, 8 * 256, stream);  // counters must start at 0 every call
    hipLaunchKernelGGL(prep_ebuf, dim3(L_TOT), dim3(EMBD), 0, stream, x, emb, E);
    hipLaunchKernelGGL(prep_wt,   dim3(1024),  dim3(1024), 0, stream, Wih_f, Whh_f, Wih_b, Whh_b, Wt);
    hipLaunchKernelGGL(prep_bias, dim3(2),     dim3(1024), 0, stream, bih_f, bhh_f, bih_b, bhh_b, bc);
    hipLaunchKernelGGL(lstm_rec,  dim3(128),   dim3(512),  0, stream, E, Wt, bc, hh, ctr);
    hipLaunchKernelGGL(out_proj,  dim3(L_TOT / 128), dim3(128), 0, stream, hh, Wout, bout, out);
    hipLaunchKernelGGL(viterbi_fv, dim3(1),    dim3(64),   0, stream, out, trans, fvh, score, best);
    hipLaunchKernelGGL(viterbi_bp, dim3((L_TOT * NTAG + 255) / 256), dim3(256), 0, stream, fvh, trans, bp);
    hipLaunchKernelGGL(backtrace, dim3(1),     dim3(1024), 0, stream, bp, best, path);
}

// Round 4
// 9969.891 us; speedup vs baseline: 1.7331x; 1.2527x over previous
//
#include <hip/hip_runtime.h>
#include <cstdint>
#include <cstddef>

// Problem constants (match reference)
#define S_LEN 256
#define BB    32
#define EMBD  256
#define HID   256
#define NTAG  10
#define L_TOT (BB*S_LEN)      // 8192 flattened viterbi length
#define NEGV  -10000.0f
#define SOS_I 1
#define EOS_I 2
#define STR   520             // st row stride (floats), 16B-aligned rows

__device__ __forceinline__ float sigf(float x) { return 1.0f / (1.0f + expf(-x)); }

// ---------------------------------------------------------------------------
// prep: gather embeddings E[t*32+b][m] = emb[x[b][t]][m]
// ---------------------------------------------------------------------------
__global__ void prep_ebuf(const int* __restrict__ x, const float* __restrict__ emb,
                          float* __restrict__ E) {
    const int row = blockIdx.x;          // t*32 + b
    const int t = row >> 5, b = row & 31;
    const int xi = x[b * S_LEN + t];
    E[(size_t)row * EMBD + threadIdx.x] = emb[(size_t)xi * EMBD + threadIdx.x];
}

// prep: Wt[d][k][j], k<256 -> Wih_d[j][k], k>=256 -> Whh_d[j][k-256]  (k-major)
__global__ void prep_wt(const float* __restrict__ Wih_f, const float* __restrict__ Whh_f,
                        const float* __restrict__ Wih_b, const float* __restrict__ Whh_b,
                        float* __restrict__ Wt) {
    const int dk = blockIdx.x;           // d*512 + k
    const int d = dk >> 9, k = dk & 511;
    const int j = threadIdx.x;           // 0..1023
    const float* src = (d == 0) ? ((k < 256) ? Wih_f : Whh_f)
                                : ((k < 256) ? Wih_b : Whh_b);
    const int kk = k & 255;
    Wt[(size_t)dk * 1024 + j] = src[(size_t)j * 256 + kk];
}

__global__ void prep_bias(const float* __restrict__ bih_f, const float* __restrict__ bhh_f,
                          const float* __restrict__ bih_b, const float* __restrict__ bhh_b,
                          float* __restrict__ bc) {
    const int idx = blockIdx.x * blockDim.x + threadIdx.x; // 0..2047
    if (idx < 1024) bc[idx] = bih_f[idx] + bhh_f[idx];
    else            bc[idx] = bih_b[idx - 1024] + bhh_b[idx - 1024];
}

// ---------------------------------------------------------------------------
// Persistent BiLSTM recurrence. 256 blocks x 512 threads (1 block/CU).
// group g = blk&15 -> (d = g>>3, bg = g&7: 4 batches); member mg = blk>>4
// (m-slice of 16). Group members share blk%8 -> same XCD under round-robin
// dispatch (perf heuristic only; agent-scope sync keeps it correct).
// 8 waves = 8 fused-K slices of 64 (k<256: e-part, k>=256: h-part).
// Lane = gate-row j (4 gates x 16 m). w[64]/lane -> ~100 VGPRs, NO SPILL
// even under the observed 128-VGPR cap (rounds 1-2 spilled w[128] -> 9.5GB).
// Inner loop reads st[b][k] wave-uniform (LDS broadcast, conflict-free).
// Sync: per-group 16-flag cacheline; store-release own flag, poll 16 relaxed.
// ---------------------------------------------------------------------------
__global__ __launch_bounds__(512, 2) void lstm_rec(
    const float* __restrict__ E,      // [8192 rows t*32+b][256]
    const float* __restrict__ Wt,     // [2][512 fused k][1024 j]
    const float* __restrict__ bc,     // [2][1024]
    float* __restrict__ hh,           // [2][256 s][32 b][256 m]
    unsigned int* __restrict__ flags) {  // [16 groups][16 members]
    const int blk = blockIdx.x;
    const int g   = blk & 15;
    const int mg  = blk >> 4;
    const int d   = g >> 3;
    const int bg  = g & 7;
    const int tid = threadIdx.x;
    const int wave = tid >> 6;
    const int lane = tid & 63;
    const int kb = wave * 64;                // fused-k base for this wave
    const int jg = (lane >> 4) * 256 + mg * 16 + (lane & 15);

    // persistent weights: w[i] = Wt[d][kb+i][jg]   (64 VGPRs)
    float w[64];
    {
        const float* wsrc = Wt + ((size_t)d * 512 + kb) * 1024 + jg;
        #pragma unroll
        for (int i = 0; i < 64; ++i) w[i] = wsrc[(size_t)i * 1024];
    }

    __shared__ __align__(16) float st[4][STR];   // [b_local][fused k 0..511]
    __shared__ float part[4][8][66];             // [b_local][wave][lane]
    __shared__ float cst[4][16];
    __shared__ float bias[64];
    if (tid < 64) bias[tid] = bc[d * 1024 + (tid >> 4) * 256 + mg * 16 + (tid & 15)];

    const int b_l = wave & 3;                // batch slot this wave stages
    const int hf_ = wave >> 2;               // which 128-half of a 256 row
    const size_t eb = ((size_t)bg * 4 + b_l) * 256 + hf_ * 128 + lane * 2;

    // stage e for s=0
    {
        const int t0 = d ? (S_LEN - 1) : 0;
        *(float2*)&st[b_l][hf_ * 128 + lane * 2] =
            *(const float2*)(E + (size_t)t0 * 32 * 256 + eb);
    }
    unsigned int* fl = flags + g * 16;
    __syncthreads();

    #pragma unroll 1
    for (int s = 0; s < S_LEN; ++s) {
        float acc[4] = {0.f, 0.f, 0.f, 0.f};
        if (!(wave >= 4 && s == 0)) {        // h-part is zero at s=0
            #pragma unroll
            for (int i = 0; i < 16; ++i) {
                #pragma unroll
                for (int b = 0; b < 4; ++b) {
                    const float4 v = *(const float4*)&st[b][kb + i * 4];  // uniform: broadcast
                    acc[b] = fmaf(v.x, w[i * 4 + 0], acc[b]);
                    acc[b] = fmaf(v.y, w[i * 4 + 1], acc[b]);
                    acc[b] = fmaf(v.z, w[i * 4 + 2], acc[b]);
                    acc[b] = fmaf(v.w, w[i * 4 + 3], acc[b]);
                }
            }
        }
        #pragma unroll
        for (int b = 0; b < 4; ++b) part[b][wave][lane] = acc[b];
        __syncthreads();

        // post: gate nonlinearities + cell update (wave 0 only -> same-wave
        // program order lets tid0's release-store cover all h-stores)
        if (tid < 64) {
            const int bl = tid >> 4, m = tid & 15;
            float vg[4];
            #pragma unroll
            for (int gg = 0; gg < 4; ++gg) {
                float v = bias[gg * 16 + m];
                #pragma unroll
                for (int q = 0; q < 8; ++q) v += part[bl][q][gg * 16 + m];
                vg[gg] = v;
            }
            const float iv = sigf(vg[0]);
            const float fv = sigf(vg[1]);
            const float gv = tanhf(vg[2]);
            const float ov = sigf(vg[3]);
            float c = (s == 0) ? 0.f : cst[bl][m];
            c = fv * c + iv * gv;
            cst[bl][m] = c;
            hh[(((size_t)d * S_LEN + s) * 32 + (bg * 4 + bl)) * 256 + mg * 16 + m] = ov * tanhf(c);
        }

        if (s < S_LEN - 1) {
            if (tid == 0)  // release: orders wave0's h-stores before the flag
                __hip_atomic_store(&fl[mg], (unsigned)(s + 1),
                                   __ATOMIC_RELEASE, __HIP_MEMORY_SCOPE_AGENT);
            // stage e for s+1 (independent of h) -> overlaps the flag wait
            {
                const int t1 = d ? (S_LEN - 2 - s) : (s + 1);
                *(float2*)&st[b_l][hf_ * 128 + lane * 2] =
                    *(const float2*)(E + (size_t)t1 * 32 * 256 + eb);
            }
            // wave0 polls all 16 member flags
            if (tid < 64) {
                const unsigned tgt = (unsigned)(s + 1);
                while (true) {
                    unsigned v = tgt;
                    if (tid < 16)
                        v = __hip_atomic_load(&fl[tid], __ATOMIC_RELAXED, __HIP_MEMORY_SCOPE_AGENT);
                    if (__all((int)(v >= tgt))) break;
                }
            }
            __syncthreads();
            __builtin_amdgcn_fence(__ATOMIC_ACQUIRE, "agent");  // acquire before reading peers' h
            // stage h of step s (now visible)
            *(float2*)&st[b_l][256 + hf_ * 128 + lane * 2] =
                *(const float2*)(hh + (((size_t)d * S_LEN + s) * 32 + bg * 4 + b_l) * 256
                                 + hf_ * 128 + lane * 2);
            __syncthreads();
        }
    }
}

// ---------------------------------------------------------------------------
// out[r][tag] = [hf | hb] . Wout[tag] + bout[tag],  r = b*256 + t
// ---------------------------------------------------------------------------
__global__ __launch_bounds__(128) void out_proj(const float* __restrict__ hh,
                                                const float* __restrict__ Wout,
                                                const float* __restrict__ bout,
                                                float* __restrict__ out) {
    const int r = blockIdx.x * blockDim.x + threadIdx.x; // 0..8191
    const int b = r >> 8, t = r & 255;
    const float* hf = hh + (((size_t)0 * S_LEN + t) * 32 + b) * 256;
    const float* hb = hh + (((size_t)1 * S_LEN + (S_LEN - 1 - t)) * 32 + b) * 256;
    float acc[NTAG];
    #pragma unroll
    for (int q = 0; q < NTAG; ++q) acc[q] = bout[q];
    for (int m = 0; m < HID; ++m) {
        const float hv = hf[m];
        #pragma unroll
        for (int q = 0; q < NTAG; ++q) acc[q] = fmaf(hv, Wout[q * 512 + m], acc[q]);
    }
    for (int m = 0; m < HID; ++m) {
        const float hv = hb[m];
        #pragma unroll
        for (int q = 0; q < NTAG; ++q) acc[q] = fmaf(hv, Wout[q * 512 + 256 + m], acc[q]);
    }
    #pragma unroll
    for (int q = 0; q < NTAG; ++q) out[(size_t)r * NTAG + q] = acc[q];
}

// ---------------------------------------------------------------------------
// Viterbi forward values (sequential, exact reference arithmetic per step).
// Lanes 0..9 = 'to'. Broadcast fvnew via v_readlane -> SGPR (no LDS latency
// in the chain); feats prefetched 8 deep (8-unrolled loop, static indices).
// ---------------------------------------------------------------------------
__global__ __launch_bounds__(64) void viterbi_fv(const float* __restrict__ feats,
                                                 const float* __restrict__ trans,
                                                 float* __restrict__ fvh,
                                                 float* __restrict__ score_out,
                                                 int* __restrict__ best_out) {
    const int lane = threadIdx.x;
    float trow[NTAG];
    #pragma unroll
    for (int f = 0; f < NTAG; ++f) trow[f] = (lane < NTAG) ? trans[lane * NTAG + f] : -3.0e38f;
    float fv[NTAG];
    #pragma unroll
    for (int f = 0; f < NTAG; ++f) fv[f] = (f == SOS_I) ? 0.f : NEGV;
    float fq[8];
    #pragma unroll
    for (int q = 0; q < 8; ++q) fq[q] = (lane < NTAG) ? feats[q * NTAG + lane] : 0.f;

    for (int r8 = 0; r8 < L_TOT; r8 += 8) {
        #pragma unroll
        for (int q = 0; q < 8; ++q) {
            const int r = r8 + q;
            float sc[NTAG];
            #pragma unroll
            for (int f = 0; f < NTAG; ++f) sc[f] = fv[f] + trow[f];
            const float m = fmaxf(fmaxf(fmaxf(fmaxf(sc[0], sc[1]), fmaxf(sc[2], sc[3])),
                                        fmaxf(fmaxf(sc[4], sc[5]), fmaxf(sc[6], sc[7]))),
                                  fmaxf(sc[8], sc[9]));
            const float fvnew = m + fq[q];
            if (lane < NTAG) fvh[(size_t)r * NTAG + lane] = fvnew;
            const int rn = r + 8;
            fq[q] = (rn < L_TOT && lane < NTAG) ? feats[(size_t)rn * NTAG + lane] : 0.f;
            #pragma unroll
            for (int f = 0; f < NTAG; ++f)
                fv[f] = __uint_as_float(__builtin_amdgcn_readlane(__float_as_uint(fvnew), f));
        }
    }

    if (lane == 0) {
        float bm = fv[0] + trans[EOS_I * NTAG + 0];
        int ba = 0;
        #pragma unroll
        for (int f = 1; f < NTAG; ++f) {
            const float tv = fv[f] + trans[EOS_I * NTAG + f];
            if (tv > bm) { bm = tv; ba = f; }   // strict > => first-max tie rule
        }
        score_out[0] = bm;
        best_out[0] = ba;
    }
}

// Backpointers, fully parallel: bptr[r][to] = first-argmax_f (fv[r-1][f] + T[to][f])
__global__ void viterbi_bp(const float* __restrict__ fvh, const float* __restrict__ trans,
                           unsigned char* __restrict__ bp) {
    const int idx = blockIdx.x * blockDim.x + threadIdx.x;
    if (idx >= L_TOT * NTAG) return;
    const int r = idx / NTAG, to = idx - r * NTAG;
    float best = 0.f;
    int arg = 0;
    #pragma unroll
    for (int f = 0; f < NTAG; ++f) {
        const float fp = r ? fvh[(size_t)(r - 1) * NTAG + f] : ((f == SOS_I) ? 0.f : NEGV);
        const float s = fp + trans[to * NTAG + f];
        if (f == 0) best = s;
        else if (s > best) { best = s; arg = f; }  // strict > => first-max
    }
    bp[idx] = (unsigned char)arg;
}

// Chunked backtrace (exact function-composition scan over [10]->[10] maps)
__global__ __launch_bounds__(1024) void backtrace(const unsigned char* __restrict__ bp,
                                                  const int* __restrict__ best_in,
                                                  float* __restrict__ path_out) {
    __shared__ unsigned char fc[128 * NTAG];
    __shared__ unsigned char topt[128];
    const int tid = threadIdx.x;
    for (int pe = tid; pe < 128 * NTAG; pe += 1024) {
        const int c = pe / NTAG, e = pe - c * NTAG;
        int cur = e;
        for (int i = 63; i >= 0; --i) cur = bp[(size_t)(c * 64 + i) * NTAG + cur];
        fc[c * NTAG + e] = (unsigned char)cur;
    }
    __syncthreads();
    if (tid == 0) {
        int carry = best_in[0];
        for (int c = 127; c >= 0; --c) {
            topt[c] = (unsigned char)carry;
            carry = fc[c * NTAG + carry];
        }
    }
    __syncthreads();
    for (int c = tid; c < 128; c += 1024) {
        int cur = topt[c];
        for (int i = 63; i >= 0; --i) {
            const int t = c * 64 + i;
            path_out[t] = (float)cur;
            cur = bp[(size_t)t * NTAG + cur];
        }
    }
}

// ---------------------------------------------------------------------------
extern "C" void kernel_launch(void* const* d_in, const int* in_sizes, int n_in,
                              void* d_out, int out_size, void* d_ws, size_t ws_size,
                              hipStream_t stream) {
    const int*   x     = (const int*)d_in[0];
    const float* emb   = (const float*)d_in[3];
    const float* Wih_f = (const float*)d_in[4];
    const float* Whh_f = (const float*)d_in[5];
    const float* bih_f = (const float*)d_in[6];
    const float* bhh_f = (const float*)d_in[7];
    const float* Wih_b = (const float*)d_in[8];
    const float* Whh_b = (const float*)d_in[9];
    const float* bih_b = (const float*)d_in[10];
    const float* bhh_b = (const float*)d_in[11];
    const float* Wout  = (const float*)d_in[12];
    const float* bout  = (const float*)d_in[13];
    const float* trans = (const float*)d_in[14];

    char* ws = (char*)d_ws;
    size_t off = 0;
    auto alloc = [&](size_t bytes) { void* p = ws + off; off += (bytes + 255) & ~(size_t)255; return p; };
    unsigned*      flags = (unsigned*)alloc(16 * 16 * 4);                 // 1 KB
    int*           best  = (int*)alloc(256);
    float*         E     = (float*)alloc((size_t)L_TOT * EMBD * 4);       // 8.4 MB
    float*         Wt    = (float*)alloc((size_t)2 * 512 * 1024 * 4);     // 4 MB
    float*         bc    = (float*)alloc(2048 * 4);
    float*         hh    = (float*)alloc((size_t)2 * S_LEN * BB * HID * 4); // 16.8 MB
    float*         fvh   = (float*)alloc((size_t)L_TOT * NTAG * 4);       // 328 KB
    unsigned char* bp    = (unsigned char*)alloc((size_t)L_TOT * NTAG);   // 80 KB

    float* out   = (float*)d_out;                  // [0 .. 81920)
    float* score = out + (size_t)L_TOT * NTAG;     // [81920]
    float* path  = score + 1;                      // [81921 .. 90113)

    (void)hipMemsetAsync(flags, 0, 16 * 16 * 4, stream);  // flags must start at 0 every call
    hipLaunchKernelGGL(prep_ebuf, dim3(L_TOT), dim3(EMBD), 0, stream, x, emb, E);
    hipLaunchKernelGGL(prep_wt,   dim3(1024),  dim3(1024), 0, stream, Wih_f, Whh_f, Wih_b, Whh_b, Wt);
    hipLaunchKernelGGL(prep_bias, dim3(2),     dim3(1024), 0, stream, bih_f, bhh_f, bih_b, bhh_b, bc);
    hipLaunchKernelGGL(lstm_rec,  dim3(256),   dim3(512),  0, stream, E, Wt, bc, hh, flags);
    hipLaunchKernelGGL(out_proj,  dim3(L_TOT / 128), dim3(128), 0, stream, hh, Wout, bout, out);
    hipLaunchKernelGGL(viterbi_fv, dim3(1),    dim3(64),   0, stream, out, trans, fvh, score, best);
    hipLaunchKernelGGL(viterbi_bp, dim3((L_TOT * NTAG + 255) / 256), dim3(256), 0, stream, fvh, trans, bp);
    hipLaunchKernelGGL(backtrace, dim3(1),     dim3(1024), 0, stream, bp, best, path);
}

// Round 5
// 6315.960 us; speedup vs baseline: 2.7358x; 1.5785x over previous
//
#include <hip/hip_runtime.h>
#include <cstdint>
#include <cstddef>

// Problem constants (match reference)
#define S_LEN 256
#define BB    32
#define EMBD  256
#define HID   256
#define NTAG  10
#define L_TOT (BB*S_LEN)      // 8192 flattened viterbi length
#define NEGV  -10000.0f
#define SOS_I 1
#define EOS_I 2
#define STR   520             // st row stride (floats), 16B-aligned rows

__device__ __forceinline__ float sigf(float x) { return 1.0f / (1.0f + expf(-x)); }

// ---------------------------------------------------------------------------
// prep: gather embeddings E[t*32+b][m] = emb[x[b][t]][m]
// ---------------------------------------------------------------------------
__global__ void prep_ebuf(const int* __restrict__ x, const float* __restrict__ emb,
                          float* __restrict__ E) {
    const int row = blockIdx.x;          // t*32 + b
    const int t = row >> 5, b = row & 31;
    const int xi = x[b * S_LEN + t];
    E[(size_t)row * EMBD + threadIdx.x] = emb[(size_t)xi * EMBD + threadIdx.x];
}

// prep: Wt[d][k][j], k<256 -> Wih_d[j][k], k>=256 -> Whh_d[j][k-256]  (k-major)
__global__ void prep_wt(const float* __restrict__ Wih_f, const float* __restrict__ Whh_f,
                        const float* __restrict__ Wih_b, const float* __restrict__ Whh_b,
                        float* __restrict__ Wt) {
    const int dk = blockIdx.x;           // d*512 + k
    const int d = dk >> 9, k = dk & 511;
    const int j = threadIdx.x;           // 0..1023
    const float* src = (d == 0) ? ((k < 256) ? Wih_f : Whh_f)
                                : ((k < 256) ? Wih_b : Whh_b);
    const int kk = k & 255;
    Wt[(size_t)dk * 1024 + j] = src[(size_t)j * 256 + kk];
}

__global__ void prep_bias(const float* __restrict__ bih_f, const float* __restrict__ bhh_f,
                          const float* __restrict__ bih_b, const float* __restrict__ bhh_b,
                          float* __restrict__ bc) {
    const int idx = blockIdx.x * blockDim.x + threadIdx.x; // 0..2047
    if (idx < 1024) bc[idx] = bih_f[idx] + bhh_f[idx];
    else            bc[idx] = bih_b[idx - 1024] + bhh_b[idx - 1024];
}

// ---------------------------------------------------------------------------
// Persistent BiLSTM recurrence. 256 blocks x 512 threads (1 block/CU).
// group g = blk&15 -> (d = g>>3, bg = g&7: 4 batches); member mg = blk>>4
// (m-slice of 16). 8 waves = 8 fused-K slices of 64.
// VGPR budget forced to 256 via amdgpu_waves_per_eu(2,2) (launch_bounds gave
// a 128 cap in rounds 1-4 -> w[64] spilled -> 8.4GB scratch FETCH/dispatch).
// Cross-block h/flag exchange uses RELAXED AGENT-scope per-element atomics
// (write-through, individually coherent): NO release/acquire fences -> no
// whole-L2 buffer_wbl2/buffer_inv per step. Ordering h-stores -> flag via
// wave-local s_waitcnt vmcnt(0) (all h-stores are wave0's own).
// ---------------------------------------------------------------------------
__global__ void __attribute__((amdgpu_flat_work_group_size(512, 512), amdgpu_waves_per_eu(2, 2)))
lstm_rec(
    const float* __restrict__ E,      // [8192 rows t*32+b][256]
    const float* __restrict__ Wt,     // [2][512 fused k][1024 j]
    const float* __restrict__ bc,     // [2][1024]
    float* __restrict__ hh,           // [2][256 s][32 b][256 m]
    unsigned int* __restrict__ flags) {  // [16 groups][16 members]
    const int blk = blockIdx.x;
    const int g   = blk & 15;
    const int mg  = blk >> 4;
    const int d   = g >> 3;
    const int bg  = g & 7;
    const int tid = threadIdx.x;
    const int wave = __builtin_amdgcn_readfirstlane(tid >> 6);
    const int lane = tid & 63;
    const int kb = wave * 64;                // fused-k base for this wave
    const int jg = (lane >> 4) * 256 + mg * 16 + (lane & 15);

    // persistent weights: w[i] = Wt[d][kb+i][jg]   (64 VGPRs)
    float w[64];
    {
        const float* wsrc = Wt + ((size_t)d * 512 + kb) * 1024 + jg;
        #pragma unroll
        for (int i = 0; i < 64; ++i) w[i] = wsrc[(size_t)i * 1024];
    }

    __shared__ __align__(16) float st[4][STR];   // [b_local][fused k 0..511]
    __shared__ float part[4][8][66];             // [b_local][wave][lane]
    __shared__ float cst[4][16];
    __shared__ float bias[64];
    if (tid < 64) bias[tid] = bc[d * 1024 + (tid >> 4) * 256 + mg * 16 + (tid & 15)];

    const int b_l = wave & 3;                // batch slot this wave stages
    const int hf_ = wave >> 2;               // which 128-half of a 256 row
    const size_t eb = ((size_t)bg * 4 + b_l) * 256 + hf_ * 128 + lane * 2;

    // stage e for s=0
    {
        const int t0 = d ? (S_LEN - 1) : 0;
        *(float2*)&st[b_l][hf_ * 128 + lane * 2] =
            *(const float2*)(E + (size_t)t0 * 32 * 256 + eb);
    }
    unsigned int* fl = flags + g * 16;
    __syncthreads();

    #pragma unroll 1
    for (int s = 0; s < S_LEN; ++s) {
        float acc[4] = {0.f, 0.f, 0.f, 0.f};
        if (!(wave >= 4 && s == 0)) {        // h-part is zero at s=0
            #pragma unroll
            for (int i = 0; i < 16; ++i) {
                #pragma unroll
                for (int b = 0; b < 4; ++b) {
                    const float4 v = *(const float4*)&st[b][kb + i * 4];  // uniform: broadcast
                    acc[b] = fmaf(v.x, w[i * 4 + 0], acc[b]);
                    acc[b] = fmaf(v.y, w[i * 4 + 1], acc[b]);
                    acc[b] = fmaf(v.z, w[i * 4 + 2], acc[b]);
                    acc[b] = fmaf(v.w, w[i * 4 + 3], acc[b]);
                }
            }
        }
        #pragma unroll
        for (int b = 0; b < 4; ++b) part[b][wave][lane] = acc[b];
        __syncthreads();

        // post: gate nonlinearities + cell update (wave 0 only); h goes out
        // as write-through agent atomics so peers never need a fence.
        if (tid < 64) {
            const int bl = tid >> 4, m = tid & 15;
            float vg[4];
            #pragma unroll
            for (int gg = 0; gg < 4; ++gg) {
                float v = bias[gg * 16 + m];
                #pragma unroll
                for (int q = 0; q < 8; ++q) v += part[bl][q][gg * 16 + m];
                vg[gg] = v;
            }
            const float iv = sigf(vg[0]);
            const float fv = sigf(vg[1]);
            const float gv = tanhf(vg[2]);
            const float ov = sigf(vg[3]);
            float c = (s == 0) ? 0.f : cst[bl][m];
            c = fv * c + iv * gv;
            cst[bl][m] = c;
            const float hv = ov * tanhf(c);
            __hip_atomic_store(
                &hh[(((size_t)d * S_LEN + s) * 32 + (bg * 4 + bl)) * 256 + mg * 16 + m],
                hv, __ATOMIC_RELAXED, __HIP_MEMORY_SCOPE_AGENT);
            if (s < S_LEN - 1) {
                // wave-local: waits this wave's (= all) h-stores to reach coherence
                asm volatile("s_waitcnt vmcnt(0)" ::: "memory");
                if (tid == 0)
                    __hip_atomic_store(&fl[mg], (unsigned)(s + 1),
                                       __ATOMIC_RELAXED, __HIP_MEMORY_SCOPE_AGENT);
            }
        }

        if (s < S_LEN - 1) {
            // stage e for s+1 (independent of h) -> overlaps the flag wait
            {
                const int t1 = d ? (S_LEN - 2 - s) : (s + 1);
                *(float2*)&st[b_l][hf_ * 128 + lane * 2] =
                    *(const float2*)(E + (size_t)t1 * 32 * 256 + eb);
            }
            // wave0 polls all 16 member flags (coherent relaxed atomic loads)
            if (tid < 64) {
                const unsigned tgt = (unsigned)(s + 1);
                while (true) {
                    unsigned v = tgt;
                    if (tid < 16)
                        v = __hip_atomic_load(&fl[tid], __ATOMIC_RELAXED, __HIP_MEMORY_SCOPE_AGENT);
                    if (__all((int)(v >= tgt))) break;
                }
            }
            __syncthreads();
            asm volatile("" ::: "memory");   // keep h loads below the poll
            // stage h of step s via coherent atomic loads (no fence needed)
            {
                const float* hsrc = hh + (((size_t)d * S_LEN + s) * 32 + bg * 4 + b_l) * 256
                                    + hf_ * 128 + lane * 2;
                const float v0 = __hip_atomic_load(hsrc,     __ATOMIC_RELAXED, __HIP_MEMORY_SCOPE_AGENT);
                const float v1 = __hip_atomic_load(hsrc + 1, __ATOMIC_RELAXED, __HIP_MEMORY_SCOPE_AGENT);
                st[b_l][256 + hf_ * 128 + lane * 2]     = v0;
                st[b_l][256 + hf_ * 128 + lane * 2 + 1] = v1;
            }
            __syncthreads();
        }
    }
}

// ---------------------------------------------------------------------------
// out[r][tag] = [hf | hb] . Wout[tag] + bout[tag],  r = b*256 + t
// ---------------------------------------------------------------------------
__global__ __launch_bounds__(128) void out_proj(const float* __restrict__ hh,
                                                const float* __restrict__ Wout,
                                                const float* __restrict__ bout,
                                                float* __restrict__ out) {
    const int r = blockIdx.x * blockDim.x + threadIdx.x; // 0..8191
    const int b = r >> 8, t = r & 255;
    const float* hf = hh + (((size_t)0 * S_LEN + t) * 32 + b) * 256;
    const float* hb = hh + (((size_t)1 * S_LEN + (S_LEN - 1 - t)) * 32 + b) * 256;
    float acc[NTAG];
    #pragma unroll
    for (int q = 0; q < NTAG; ++q) acc[q] = bout[q];
    for (int m = 0; m < HID; ++m) {
        const float hv = hf[m];
        #pragma unroll
        for (int q = 0; q < NTAG; ++q) acc[q] = fmaf(hv, Wout[q * 512 + m], acc[q]);
    }
    for (int m = 0; m < HID; ++m) {
        const float hv = hb[m];
        #pragma unroll
        for (int q = 0; q < NTAG; ++q) acc[q] = fmaf(hv, Wout[q * 512 + 256 + m], acc[q]);
    }
    #pragma unroll
    for (int q = 0; q < NTAG; ++q) out[(size_t)r * NTAG + q] = acc[q];
}

// ---------------------------------------------------------------------------
// Viterbi forward values (sequential, exact reference arithmetic per step).
// Lanes 0..9 = 'to'. Broadcast fvnew via v_readlane -> SGPR; feats prefetched
// 8 deep (8-unrolled loop, static indices).
// ---------------------------------------------------------------------------
__global__ __launch_bounds__(64) void viterbi_fv(const float* __restrict__ feats,
                                                 const float* __restrict__ trans,
                                                 float* __restrict__ fvh,
                                                 float* __restrict__ score_out,
                                                 int* __restrict__ best_out) {
    const int lane = threadIdx.x;
    float trow[NTAG];
    #pragma unroll
    for (int f = 0; f < NTAG; ++f) trow[f] = (lane < NTAG) ? trans[lane * NTAG + f] : -3.0e38f;
    float fv[NTAG];
    #pragma unroll
    for (int f = 0; f < NTAG; ++f) fv[f] = (f == SOS_I) ? 0.f : NEGV;
    float fq[8];
    #pragma unroll
    for (int q = 0; q < 8; ++q) fq[q] = (lane < NTAG) ? feats[q * NTAG + lane] : 0.f;

    for (int r8 = 0; r8 < L_TOT; r8 += 8) {
        #pragma unroll
        for (int q = 0; q < 8; ++q) {
            const int r = r8 + q;
            float sc[NTAG];
            #pragma unroll
            for (int f = 0; f < NTAG; ++f) sc[f] = fv[f] + trow[f];
            const float m = fmaxf(fmaxf(fmaxf(fmaxf(sc[0], sc[1]), fmaxf(sc[2], sc[3])),
                                        fmaxf(fmaxf(sc[4], sc[5]), fmaxf(sc[6], sc[7]))),
                                  fmaxf(sc[8], sc[9]));
            const float fvnew = m + fq[q];
            if (lane < NTAG) fvh[(size_t)r * NTAG + lane] = fvnew;
            const int rn = r + 8;
            fq[q] = (rn < L_TOT && lane < NTAG) ? feats[(size_t)rn * NTAG + lane] : 0.f;
            #pragma unroll
            for (int f = 0; f < NTAG; ++f)
                fv[f] = __uint_as_float(__builtin_amdgcn_readlane(__float_as_uint(fvnew), f));
        }
    }

    if (lane == 0) {
        float bm = fv[0] + trans[EOS_I * NTAG + 0];
        int ba = 0;
        #pragma unroll
        for (int f = 1; f < NTAG; ++f) {
            const float tv = fv[f] + trans[EOS_I * NTAG + f];
            if (tv > bm) { bm = tv; ba = f; }   // strict > => first-max tie rule
        }
        score_out[0] = bm;
        best_out[0] = ba;
    }
}

// Backpointers, fully parallel: bptr[r][to] = first-argmax_f (fv[r-1][f] + T[to][f])
__global__ void viterbi_bp(const float* __restrict__ fvh, const float* __restrict__ trans,
                           unsigned char* __restrict__ bp) {
    const int idx = blockIdx.x * blockDim.x + threadIdx.x;
    if (idx >= L_TOT * NTAG) return;
    const int r = idx / NTAG, to = idx - r * NTAG;
    float best = 0.f;
    int arg = 0;
    #pragma unroll
    for (int f = 0; f < NTAG; ++f) {
        const float fp = r ? fvh[(size_t)(r - 1) * NTAG + f] : ((f == SOS_I) ? 0.f : NEGV);
        const float s = fp + trans[to * NTAG + f];
        if (f == 0) best = s;
        else if (s > best) { best = s; arg = f; }  // strict > => first-max
    }
    bp[idx] = (unsigned char)arg;
}

// Chunked backtrace (exact function-composition scan over [10]->[10] maps)
__global__ __launch_bounds__(1024) void backtrace(const unsigned char* __restrict__ bp,
                                                  const int* __restrict__ best_in,
                                                  float* __restrict__ path_out) {
    __shared__ unsigned char fc[128 * NTAG];
    __shared__ unsigned char topt[128];
    const int tid = threadIdx.x;
    for (int pe = tid; pe < 128 * NTAG; pe += 1024) {
        const int c = pe / NTAG, e = pe - c * NTAG;
        int cur = e;
        for (int i = 63; i >= 0; --i) cur = bp[(size_t)(c * 64 + i) * NTAG + cur];
        fc[c * NTAG + e] = (unsigned char)cur;
    }
    __syncthreads();
    if (tid == 0) {
        int carry = best_in[0];
        for (int c = 127; c >= 0; --c) {
            topt[c] = (unsigned char)carry;
            carry = fc[c * NTAG + carry];
        }
    }
    __syncthreads();
    for (int c = tid; c < 128; c += 1024) {
        int cur = topt[c];
        for (int i = 63; i >= 0; --i) {
            const int t = c * 64 + i;
            path_out[t] = (float)cur;
            cur = bp[(size_t)t * NTAG + cur];
        }
    }
}

// ---------------------------------------------------------------------------
extern "C" void kernel_launch(void* const* d_in, const int* in_sizes, int n_in,
                              void* d_out, int out_size, void* d_ws, size_t ws_size,
                              hipStream_t stream) {
    const int*   x     = (const int*)d_in[0];
    const float* emb   = (const float*)d_in[3];
    const float* Wih_f = (const float*)d_in[4];
    const float* Whh_f = (const float*)d_in[5];
    const float* bih_f = (const float*)d_in[6];
    const float* bhh_f = (const float*)d_in[7];
    const float* Wih_b = (const float*)d_in[8];
    const float* Whh_b = (const float*)d_in[9];
    const float* bih_b = (const float*)d_in[10];
    const float* bhh_b = (const float*)d_in[11];
    const float* Wout  = (const float*)d_in[12];
    const float* bout  = (const float*)d_in[13];
    const float* trans = (const float*)d_in[14];

    char* ws = (char*)d_ws;
    size_t off = 0;
    auto alloc = [&](size_t bytes) { void* p = ws + off; off += (bytes + 255) & ~(size_t)255; return p; };
    unsigned*      flags = (unsigned*)alloc(16 * 16 * 4);                 // 1 KB
    int*           best  = (int*)alloc(256);
    float*         E     = (float*)alloc((size_t)L_TOT * EMBD * 4);       // 8.4 MB
    float*         Wt    = (float*)alloc((size_t)2 * 512 * 1024 * 4);     // 4 MB
    float*         bc    = (float*)alloc(2048 * 4);
    float*         hh    = (float*)alloc((size_t)2 * S_LEN * BB * HID * 4); // 16.8 MB
    float*         fvh   = (float*)alloc((size_t)L_TOT * NTAG * 4);       // 328 KB
    unsigned char* bp    = (unsigned char*)alloc((size_t)L_TOT * NTAG);   // 80 KB

    float* out   = (float*)d_out;                  // [0 .. 81920)
    float* score = out + (size_t)L_TOT * NTAG;     // [81920]
    float* path  = score + 1;                      // [81921 .. 90113)

    (void)hipMemsetAsync(flags, 0, 16 * 16 * 4, stream);  // flags must start at 0 every call
    hipLaunchKernelGGL(prep_ebuf, dim3(L_TOT), dim3(EMBD), 0, stream, x, emb, E);
    hipLaunchKernelGGL(prep_wt,   dim3(1024),  dim3(1024), 0, stream, Wih_f, Whh_f, Wih_b, Whh_b, Wt);
    hipLaunchKernelGGL(prep_bias, dim3(2),     dim3(1024), 0, stream, bih_f, bhh_f, bih_b, bhh_b, bc);
    hipLaunchKernelGGL(lstm_rec,  dim3(256),   dim3(512),  0, stream, E, Wt, bc, hh, flags);
    hipLaunchKernelGGL(out_proj,  dim3(L_TOT / 128), dim3(128), 0, stream, hh, Wout, bout, out);
    hipLaunchKernelGGL(viterbi_fv, dim3(1),    dim3(64),   0, stream, out, trans, fvh, score, best);
    hipLaunchKernelGGL(viterbi_bp, dim3((L_TOT * NTAG + 255) / 256), dim3(256), 0, stream, fvh, trans, bp);
    hipLaunchKernelGGL(backtrace, dim3(1),     dim3(1024), 0, stream, bp, best, path);
}

// Round 6
// 1783.614 us; speedup vs baseline: 9.6876x; 3.5411x over previous
//
#include <hip/hip_runtime.h>
#include <cstdint>
#include <cstddef>

// Problem constants (match reference)
#define S_LEN 256
#define BB    32
#define EMBD  256
#define HID   256
#define NTAG  10
#define L_TOT (BB*S_LEN)      // 8192 flattened viterbi length
#define NEGV  -10000.0f
#define SOS_I 1
#define EOS_I 2
#define STR   520             // st row stride (floats), 16B-aligned rows

__device__ __forceinline__ float sigf(float x) { return 1.0f / (1.0f + expf(-x)); }

// ---------------------------------------------------------------------------
// prep: gather embeddings E[t*32+b][m] = emb[x[b][t]][m]
// ---------------------------------------------------------------------------
__global__ void prep_ebuf(const int* __restrict__ x, const float* __restrict__ emb,
                          float* __restrict__ E) {
    const int row = blockIdx.x;          // t*32 + b
    const int t = row >> 5, b = row & 31;
    const int xi = x[b * S_LEN + t];
    E[(size_t)row * EMBD + threadIdx.x] = emb[(size_t)xi * EMBD + threadIdx.x];
}

// prep: Wt[d][k][j], k<256 -> Wih_d[j][k], k>=256 -> Whh_d[j][k-256]  (k-major)
__global__ void prep_wt(const float* __restrict__ Wih_f, const float* __restrict__ Whh_f,
                        const float* __restrict__ Wih_b, const float* __restrict__ Whh_b,
                        float* __restrict__ Wt) {
    const int dk = blockIdx.x;           // d*512 + k
    const int d = dk >> 9, k = dk & 511;
    const int j = threadIdx.x;           // 0..1023
    const float* src = (d == 0) ? ((k < 256) ? Wih_f : Whh_f)
                                : ((k < 256) ? Wih_b : Whh_b);
    const int kk = k & 255;
    Wt[(size_t)dk * 1024 + j] = src[(size_t)j * 256 + kk];
}

__global__ void prep_bias(const float* __restrict__ bih_f, const float* __restrict__ bhh_f,
                          const float* __restrict__ bih_b, const float* __restrict__ bhh_b,
                          float* __restrict__ bc) {
    const int idx = blockIdx.x * blockDim.x + threadIdx.x; // 0..2047
    if (idx < 1024) bc[idx] = bih_f[idx] + bhh_f[idx];
    else            bc[idx] = bih_b[idx - 1024] + bhh_b[idx - 1024];
}

// ---------------------------------------------------------------------------
// Persistent BiLSTM recurrence. 256 blocks x 1024 threads (1 block/CU).
// group g = blk&15 -> (d = g>>3, bg = g&7: 4 batches); member mg = blk>>4
// (m-slice of 16). 16 waves = 16 fused-K slices of 32 (k<256: e, k>=256: h).
// w[32]/lane: ~95 VGPRs incl. pipeline -> fits the default 128 cap WITHOUT
// spilling (rounds 1-5: w[64] + aggressive unroll spilled -> 8.4GB/dispatch).
// Inner k-loop unrolled only 2x to bound live float4 LDS results (~8 = 32 regs).
// Cross-block h/flag exchange: RELAXED AGENT-scope per-element atomics (no
// whole-L2 fences); h-stores -> flag ordered by wave-local s_waitcnt vmcnt(0)
// (all h-stores and the flag store are wave0's own).
// ---------------------------------------------------------------------------
__global__ __launch_bounds__(1024) void lstm_rec(
    const float* __restrict__ E,      // [8192 rows t*32+b][256]
    const float* __restrict__ Wt,     // [2][512 fused k][1024 j]
    const float* __restrict__ bc,     // [2][1024]
    float* __restrict__ hh,           // [2][256 s][32 b][256 m]
    unsigned int* __restrict__ flags) {  // [16 groups][16 members]
    const int blk = blockIdx.x;
    const int g   = blk & 15;
    const int mg  = blk >> 4;
    const int d   = g >> 3;
    const int bg  = g & 7;
    const int tid = threadIdx.x;
    const int wave = __builtin_amdgcn_readfirstlane(tid >> 6);  // 0..15
    const int lane = tid & 63;
    const int kb = wave * 32;                // fused-k base for this wave
    const int jg = (lane >> 4) * 256 + mg * 16 + (lane & 15);

    // persistent weights: w[i] = Wt[d][kb+i][jg]   (32 VGPRs)
    float w[32];
    {
        const float* wsrc = Wt + ((size_t)d * 512 + kb) * 1024 + jg;
        #pragma unroll
        for (int i = 0; i < 32; ++i) w[i] = wsrc[(size_t)i * 1024];
    }

    __shared__ __align__(16) float st[4][STR];   // [b_local][fused k 0..511]
    __shared__ float part[4][16][66];            // [b_local][wave][lane]
    __shared__ float cst[4][16];
    __shared__ float bias[64];
    if (tid < 64) bias[tid] = bc[d * 1024 + (tid >> 4) * 256 + mg * 16 + (tid & 15)];

    const int b_l = wave & 3;                // batch slot this wave stages
    const int q4  = wave >> 2;               // quarter (64 floats) of a 256 row
    const int so  = q4 * 64 + lane;          // element offset within the row
    const size_t erow = (size_t)(bg * 4 + b_l);

    // stage e for s=0 (1 float/lane, coalesced 256B/wave)
    {
        const int t0 = d ? (S_LEN - 1) : 0;
        st[b_l][so] = E[((size_t)t0 * 32 + erow) * 256 + so];
    }
    unsigned int* fl = flags + g * 16;
    __syncthreads();

    #pragma unroll 1
    for (int s = 0; s < S_LEN; ++s) {
        float acc[4] = {0.f, 0.f, 0.f, 0.f};
        if (!(wave >= 8 && s == 0)) {        // h-part is zero at s=0
            #pragma unroll 2
            for (int i = 0; i < 8; ++i) {
                #pragma unroll
                for (int b = 0; b < 4; ++b) {
                    const float4 v = *(const float4*)&st[b][kb + i * 4];  // uniform: broadcast
                    acc[b] = fmaf(v.x, w[i * 4 + 0], acc[b]);
                    acc[b] = fmaf(v.y, w[i * 4 + 1], acc[b]);
                    acc[b] = fmaf(v.z, w[i * 4 + 2], acc[b]);
                    acc[b] = fmaf(v.w, w[i * 4 + 3], acc[b]);
                }
            }
        }
        #pragma unroll
        for (int b = 0; b < 4; ++b) part[b][wave][lane] = acc[b];
        __syncthreads();

        // post: gate nonlinearities + cell update (wave 0 only); h goes out
        // as write-through agent atomics so peers never need a fence.
        if (tid < 64) {
            const int bl = tid >> 4, m = tid & 15;
            float vg[4];
            #pragma unroll
            for (int gg = 0; gg < 4; ++gg) {
                float v = bias[gg * 16 + m];
                #pragma unroll
                for (int q = 0; q < 16; ++q) v += part[bl][q][gg * 16 + m];
                vg[gg] = v;
            }
            const float iv = sigf(vg[0]);
            const float fv = sigf(vg[1]);
            const float gv = tanhf(vg[2]);
            const float ov = sigf(vg[3]);
            float c = (s == 0) ? 0.f : cst[bl][m];
            c = fv * c + iv * gv;
            cst[bl][m] = c;
            const float hv = ov * tanhf(c);
            __hip_atomic_store(
                &hh[(((size_t)d * S_LEN + s) * 32 + (bg * 4 + bl)) * 256 + mg * 16 + m],
                hv, __ATOMIC_RELAXED, __HIP_MEMORY_SCOPE_AGENT);
            if (s < S_LEN - 1) {
                // wave-local: waits this wave's (= all) h-stores to reach coherence
                asm volatile("s_waitcnt vmcnt(0)" ::: "memory");
                if (tid == 0)
                    __hip_atomic_store(&fl[mg], (unsigned)(s + 1),
                                       __ATOMIC_RELAXED, __HIP_MEMORY_SCOPE_AGENT);
            }
        }

        if (s < S_LEN - 1) {
            // stage e for s+1 (independent of h) -> overlaps the flag wait
            {
                const int t1 = d ? (S_LEN - 2 - s) : (s + 1);
                st[b_l][so] = E[((size_t)t1 * 32 + erow) * 256 + so];
            }
            // wave0 polls all 16 member flags (coherent relaxed atomic loads)
            if (tid < 64) {
                const unsigned tgt = (unsigned)(s + 1);
                while (true) {
                    unsigned v = tgt;
                    if (tid < 16)
                        v = __hip_atomic_load(&fl[tid], __ATOMIC_RELAXED, __HIP_MEMORY_SCOPE_AGENT);
                    if (__all((int)(v >= tgt))) break;
                }
            }
            __syncthreads();
            asm volatile("" ::: "memory");   // keep h loads below the poll
            // stage h of step s via coherent atomic load (no fence needed)
            st[b_l][256 + so] = __hip_atomic_load(
                hh + (((size_t)d * S_LEN + s) * 32 + bg * 4 + b_l) * 256 + so,
                __ATOMIC_RELAXED, __HIP_MEMORY_SCOPE_AGENT);
            __syncthreads();
        }
    }
}

// ---------------------------------------------------------------------------
// out[r][tag] = [hf | hb] . Wout[tag] + bout[tag],  r = b*256 + t
// ---------------------------------------------------------------------------
__global__ __launch_bounds__(128) void out_proj(const float* __restrict__ hh,
                                                const float* __restrict__ Wout,
                                                const float* __restrict__ bout,
                                                float* __restrict__ out) {
    const int r = blockIdx.x * blockDim.x + threadIdx.x; // 0..8191
    const int b = r >> 8, t = r & 255;
    const float* hf = hh + (((size_t)0 * S_LEN + t) * 32 + b) * 256;
    const float* hb = hh + (((size_t)1 * S_LEN + (S_LEN - 1 - t)) * 32 + b) * 256;
    float acc[NTAG];
    #pragma unroll
    for (int q = 0; q < NTAG; ++q) acc[q] = bout[q];
    for (int m = 0; m < HID; ++m) {
        const float hv = hf[m];
        #pragma unroll
        for (int q = 0; q < NTAG; ++q) acc[q] = fmaf(hv, Wout[q * 512 + m], acc[q]);
    }
    for (int m = 0; m < HID; ++m) {
        const float hv = hb[m];
        #pragma unroll
        for (int q = 0; q < NTAG; ++q) acc[q] = fmaf(hv, Wout[q * 512 + 256 + m], acc[q]);
    }
    #pragma unroll
    for (int q = 0; q < NTAG; ++q) out[(size_t)r * NTAG + q] = acc[q];
}

// ---------------------------------------------------------------------------
// Viterbi forward values (sequential, exact reference arithmetic per step).
// Lanes 0..9 = 'to'. Broadcast fvnew via v_readlane -> SGPR; feats prefetched
// 8 deep (8-unrolled loop, static indices).
// ---------------------------------------------------------------------------
__global__ __launch_bounds__(64) void viterbi_fv(const float* __restrict__ feats,
                                                 const float* __restrict__ trans,
                                                 float* __restrict__ fvh,
                                                 float* __restrict__ score_out,
                                                 int* __restrict__ best_out) {
    const int lane = threadIdx.x;
    float trow[NTAG];
    #pragma unroll
    for (int f = 0; f < NTAG; ++f) trow[f] = (lane < NTAG) ? trans[lane * NTAG + f] : -3.0e38f;
    float fv[NTAG];
    #pragma unroll
    for (int f = 0; f < NTAG; ++f) fv[f] = (f == SOS_I) ? 0.f : NEGV;
    float fq[8];
    #pragma unroll
    for (int q = 0; q < 8; ++q) fq[q] = (lane < NTAG) ? feats[q * NTAG + lane] : 0.f;

    for (int r8 = 0; r8 < L_TOT; r8 += 8) {
        #pragma unroll
        for (int q = 0; q < 8; ++q) {
            const int r = r8 + q;
            float sc[NTAG];
            #pragma unroll
            for (int f = 0; f < NTAG; ++f) sc[f] = fv[f] + trow[f];
            const float m = fmaxf(fmaxf(fmaxf(fmaxf(sc[0], sc[1]), fmaxf(sc[2], sc[3])),
                                        fmaxf(fmaxf(sc[4], sc[5]), fmaxf(sc[6], sc[7]))),
                                  fmaxf(sc[8], sc[9]));
            const float fvnew = m + fq[q];
            if (lane < NTAG) fvh[(size_t)r * NTAG + lane] = fvnew;
            const int rn = r + 8;
            fq[q] = (rn < L_TOT && lane < NTAG) ? feats[(size_t)rn * NTAG + lane] : 0.f;
            #pragma unroll
            for (int f = 0; f < NTAG; ++f)
                fv[f] = __uint_as_float(__builtin_amdgcn_readlane(__float_as_uint(fvnew), f));
        }
    }

    if (lane == 0) {
        float bm = fv[0] + trans[EOS_I * NTAG + 0];
        int ba = 0;
        #pragma unroll
        for (int f = 1; f < NTAG; ++f) {
            const float tv = fv[f] + trans[EOS_I * NTAG + f];
            if (tv > bm) { bm = tv; ba = f; }   // strict > => first-max tie rule
        }
        score_out[0] = bm;
        best_out[0] = ba;
    }
}

// Backpointers, fully parallel: bptr[r][to] = first-argmax_f (fv[r-1][f] + T[to][f])
__global__ void viterbi_bp(const float* __restrict__ fvh, const float* __restrict__ trans,
                           unsigned char* __restrict__ bp) {
    const int idx = blockIdx.x * blockDim.x + threadIdx.x;
    if (idx >= L_TOT * NTAG) return;
    const int r = idx / NTAG, to = idx - r * NTAG;
    float best = 0.f;
    int arg = 0;
    #pragma unroll
    for (int f = 0; f < NTAG; ++f) {
        const float fp = r ? fvh[(size_t)(r - 1) * NTAG + f] : ((f == SOS_I) ? 0.f : NEGV);
        const float s = fp + trans[to * NTAG + f];
        if (f == 0) best = s;
        else if (s > best) { best = s; arg = f; }  // strict > => first-max
    }
    bp[idx] = (unsigned char)arg;
}

// Chunked backtrace (exact function-composition scan over [10]->[10] maps)
__global__ __launch_bounds__(1024) void backtrace(const unsigned char* __restrict__ bp,
                                                  const int* __restrict__ best_in,
                                                  float* __restrict__ path_out) {
    __shared__ unsigned char fc[128 * NTAG];
    __shared__ unsigned char topt[128];
    const int tid = threadIdx.x;
    for (int pe = tid; pe < 128 * NTAG; pe += 1024) {
        const int c = pe / NTAG, e = pe - c * NTAG;
        int cur = e;
        for (int i = 63; i >= 0; --i) cur = bp[(size_t)(c * 64 + i) * NTAG + cur];
        fc[c * NTAG + e] = (unsigned char)cur;
    }
    __syncthreads();
    if (tid == 0) {
        int carry = best_in[0];
        for (int c = 127; c >= 0; --c) {
            topt[c] = (unsigned char)carry;
            carry = fc[c * NTAG + carry];
        }
    }
    __syncthreads();
    for (int c = tid; c < 128; c += 1024) {
        int cur = topt[c];
        for (int i = 63; i >= 0; --i) {
            const int t = c * 64 + i;
            path_out[t] = (float)cur;
            cur = bp[(size_t)t * NTAG + cur];
        }
    }
}

// ---------------------------------------------------------------------------
extern "C" void kernel_launch(void* const* d_in, const int* in_sizes, int n_in,
                              void* d_out, int out_size, void* d_ws, size_t ws_size,
                              hipStream_t stream) {
    const int*   x     = (const int*)d_in[0];
    const float* emb   = (const float*)d_in[3];
    const float* Wih_f = (const float*)d_in[4];
    const float* Whh_f = (const float*)d_in[5];
    const float* bih_f = (const float*)d_in[6];
    const float* bhh_f = (const float*)d_in[7];
    const float* Wih_b = (const float*)d_in[8];
    const float* Whh_b = (const float*)d_in[9];
    const float* bih_b = (const float*)d_in[10];
    const float* bhh_b = (const float*)d_in[11];
    const float* Wout  = (const float*)d_in[12];
    const float* bout  = (const float*)d_in[13];
    const float* trans = (const float*)d_in[14];

    char* ws = (char*)d_ws;
    size_t off = 0;
    auto alloc = [&](size_t bytes) { void* p = ws + off; off += (bytes + 255) & ~(size_t)255; return p; };
    unsigned*      flags = (unsigned*)alloc(16 * 16 * 4);                 // 1 KB
    int*           best  = (int*)alloc(256);
    float*         E     = (float*)alloc((size_t)L_TOT * EMBD * 4);       // 8.4 MB
    float*         Wt    = (float*)alloc((size_t)2 * 512 * 1024 * 4);     // 4 MB
    float*         bc    = (float*)alloc(2048 * 4);
    float*         hh    = (float*)alloc((size_t)2 * S_LEN * BB * HID * 4); // 16.8 MB
    float*         fvh   = (float*)alloc((size_t)L_TOT * NTAG * 4);       // 328 KB
    unsigned char* bp    = (unsigned char*)alloc((size_t)L_TOT * NTAG);   // 80 KB

    float* out   = (float*)d_out;                  // [0 .. 81920)
    float* score = out + (size_t)L_TOT * NTAG;     // [81920]
    float* path  = score + 1;                      // [81921 .. 90113)

    (void)hipMemsetAsync(flags, 0, 16 * 16 * 4, stream);  // flags must start at 0 every call
    hipLaunchKernelGGL(prep_ebuf, dim3(L_TOT), dim3(EMBD), 0, stream, x, emb, E);
    hipLaunchKernelGGL(prep_wt,   dim3(1024),  dim3(1024), 0, stream, Wih_f, Whh_f, Wih_b, Whh_b, Wt);
    hipLaunchKernelGGL(prep_bias, dim3(2),     dim3(1024), 0, stream, bih_f, bhh_f, bih_b, bhh_b, bc);
    hipLaunchKernelGGL(lstm_rec,  dim3(256),   dim3(1024), 0, stream, E, Wt, bc, hh, flags);
    hipLaunchKernelGGL(out_proj,  dim3(L_TOT / 128), dim3(128), 0, stream, hh, Wout, bout, out);
    hipLaunchKernelGGL(viterbi_fv, dim3(1),    dim3(64),   0, stream, out, trans, fvh, score, best);
    hipLaunchKernelGGL(viterbi_bp, dim3((L_TOT * NTAG + 255) / 256), dim3(256), 0, stream, fvh, trans, bp);
    hipLaunchKernelGGL(backtrace, dim3(1),     dim3(1024), 0, stream, bp, best, path);
}